// Round 3
// baseline (465.098 us; speedup 1.0000x reference)
//
#include <hip/hip_runtime.h>
#include <stdint.h>

// MixLinear (LLM.int8-style): dynamic per-row quant + int8 MFMA GEMM +
// fused dequant/bias + rank-32 fp16 outlier-correction MFMA.
// R2/R3: dtype fix — x/scale_col/weight_cache are float32, q_weight is int32,
// output is float32 (harness promotes fp16->f32, int8->int32).

typedef float    f32x4  __attribute__((ext_vector_type(4)));
typedef int      i32x4  __attribute__((ext_vector_type(4)));
typedef _Float16 half8  __attribute__((ext_vector_type(8)));
typedef _Float16 half4  __attribute__((ext_vector_type(4)));

#define MTOT 8192
#define NTOT 4096
#define KTOT 4096

// ---------- kernel 0: pack int32 weights -> int8; weight_cache f32 -> f16 ---
__global__ __launch_bounds__(256) void pack_kernel(
    const int* __restrict__ qw32, int8_t* __restrict__ qw8,
    const float* __restrict__ wc, _Float16* __restrict__ wch)
{
  const int bid = blockIdx.x;
  if (bid < 4096) {
    const int base = (bid * 256 + threadIdx.x) * 16;
    const i32x4* p = (const i32x4*)(qw32 + base);
    uint32_t o[4];
#pragma unroll
    for (int g = 0; g < 4; ++g) {
      const i32x4 v = p[g];
      o[g] = (uint32_t)(v[0] & 255) | ((uint32_t)(v[1] & 255) << 8) |
             ((uint32_t)(v[2] & 255) << 16) | ((uint32_t)(v[3] & 255) << 24);
    }
    *(i32x4*)(qw8 + base) = i32x4{(int)o[0], (int)o[1], (int)o[2], (int)o[3]};
  } else {
    const int idx = ((bid - 4096) * 256 + threadIdx.x) * 4;  // 128 blks * 1024 = 131072
    const float4 v = *(const float4*)(wc + idx);
    half4 h = {(_Float16)v.x, (_Float16)v.y, (_Float16)v.z, (_Float16)v.w};
    *(half4*)(wch + idx) = h;
  }
}

// ---------- kernel 1: per-row absmax, quantize to int8, gather outliers ----
__global__ __launch_bounds__(256) void quant_kernel(
    const float* __restrict__ x, const int* __restrict__ ind,
    int8_t* __restrict__ qx, float* __restrict__ srow, _Float16* __restrict__ xo)
{
  const int row = blockIdx.x;
  const int t = threadIdx.x;
  const float* xrow = x + (size_t)row * KTOT;
  const float4* xr = (const float4*)xrow;
  float4 v[4];
#pragma unroll
  for (int g = 0; g < 4; ++g) v[g] = xr[4 * t + g];  // elems 16t .. 16t+15

  float am = 0.f;
#pragma unroll
  for (int g = 0; g < 4; ++g) {
    am = fmaxf(am, fmaxf(fmaxf(fabsf(v[g].x), fabsf(v[g].y)),
                         fmaxf(fabsf(v[g].z), fabsf(v[g].w))));
  }
#pragma unroll
  for (int off = 32; off; off >>= 1)
    am = fmaxf(am, __shfl_xor(am, off, 64));
  __shared__ float red[4];
  if ((t & 63) == 0) red[t >> 6] = am;
  __syncthreads();
  am = fmaxf(fmaxf(red[0], red[1]), fmaxf(red[2], red[3]));

  const float rscale = 127.0f / am;  // scale_row = am/127

  uint32_t o[4];
#pragma unroll
  for (int g = 0; g < 4; ++g) {
    const float4 w = v[g];
    const int q0 = (int)rintf(fminf(fmaxf(w.x * rscale, -128.f), 127.f));
    const int q1 = (int)rintf(fminf(fmaxf(w.y * rscale, -128.f), 127.f));
    const int q2 = (int)rintf(fminf(fmaxf(w.z * rscale, -128.f), 127.f));
    const int q3 = (int)rintf(fminf(fmaxf(w.w * rscale, -128.f), 127.f));
    o[g] = (uint32_t)(q0 & 255) | ((uint32_t)(q1 & 255) << 8) |
           ((uint32_t)(q2 & 255) << 16) | ((uint32_t)(q3 & 255) << 24);
  }
  *(i32x4*)(qx + (size_t)row * KTOT + 16 * t) =
      i32x4{(int)o[0], (int)o[1], (int)o[2], (int)o[3]};

  if (t < 32) xo[row * 32 + t] = (_Float16)xrow[ind[t]];
  if (t == 0) srow[row] = am / 127.0f;
}

// ---------- kernel 2: int8 GEMM + dequant + bias + fp16 outlier MFMA -------
// 128x128 tile, 4 waves 2x2, each wave 64x64 via 4x4 mfma_i32_16x16x64_i8.
// LDS tiles [128 rows][64 B], 16B chunks XOR-swizzled: slot = c ^ (row&3).
__global__ __launch_bounds__(256) void mixgemm_kernel(
    const int8_t* __restrict__ qx, const int8_t* __restrict__ qw,
    const float* __restrict__ srow, const float* __restrict__ sc,
    const _Float16* __restrict__ xo, const _Float16* __restrict__ wc,
    float* __restrict__ out)
{
  __shared__ int8_t lA[128 * 64];
  __shared__ int8_t lB[128 * 64];

  const int t = threadIdx.x;
  const int lane = t & 63;
  const int wid = t >> 6;
  const int wm = wid >> 1, wn = wid & 1;
  const int bx = blockIdx.x;
  const int tn = bx & 31;   // NTOT/128 = 32
  const int tm = bx >> 5;
  const int bm0 = tm * 128, bn0 = tn * 128;

  // staging: 512 chunks of 16B per tile; thread handles chunks t and t+256
  const int idx0 = t, idx1 = t + 256;
  const int r0 = idx0 >> 2, c0 = idx0 & 3;
  const int r1 = idx1 >> 2, c1 = idx1 & 3;
  const int w0 = r0 * 64 + ((c0 ^ (r0 & 3)) * 16);  // swizzled LDS byte offset
  const int w1 = r1 * 64 + ((c1 ^ (r1 & 3)) * 16);
  const int8_t* gA0 = qx + (size_t)(bm0 + r0) * KTOT + c0 * 16;
  const int8_t* gA1 = qx + (size_t)(bm0 + r1) * KTOT + c1 * 16;
  const int8_t* gB0 = qw + (size_t)(bn0 + r0) * KTOT + c0 * 16;
  const int8_t* gB1 = qw + (size_t)(bn0 + r1) * KTOT + c1 * 16;

  // fragment ds_read offsets (A rows = wave M strip, B rows = wave N strip)
  int roA[4], roB[4];
#pragma unroll
  for (int i = 0; i < 4; ++i) {
    const int ra = wm * 64 + i * 16 + (lane & 15);
    roA[i] = ra * 64 + (((lane >> 4) ^ (ra & 3)) * 16);
    const int rb = wn * 64 + i * 16 + (lane & 15);
    roB[i] = rb * 64 + (((lane >> 4) ^ (rb & 3)) * 16);
  }

  i32x4 acc[4][4];
#pragma unroll
  for (int i = 0; i < 4; ++i)
#pragma unroll
    for (int j = 0; j < 4; ++j) acc[i][j] = i32x4{0, 0, 0, 0};

  for (int kt = 0; kt < KTOT; kt += 64) {
    const i32x4 sa0 = *(const i32x4*)(gA0 + kt);
    const i32x4 sa1 = *(const i32x4*)(gA1 + kt);
    const i32x4 sb0 = *(const i32x4*)(gB0 + kt);
    const i32x4 sb1 = *(const i32x4*)(gB1 + kt);
    __syncthreads();  // previous iter's ds_reads done before overwrite
    *(i32x4*)(lA + w0) = sa0;
    *(i32x4*)(lA + w1) = sa1;
    *(i32x4*)(lB + w0) = sb0;
    *(i32x4*)(lB + w1) = sb1;
    __syncthreads();
    i32x4 af[4], bfr[4];
#pragma unroll
    for (int i = 0; i < 4; ++i) {
      af[i]  = *(const i32x4*)(lA + roA[i]);
      bfr[i] = *(const i32x4*)(lB + roB[i]);
    }
#pragma unroll
    for (int i = 0; i < 4; ++i)
#pragma unroll
      for (int j = 0; j < 4; ++j)
        acc[i][j] = __builtin_amdgcn_mfma_i32_16x16x64_i8(af[i], bfr[j], acc[i][j], 0, 0, 0);
  }

  // ---- outlier correction: corr = xo_tile (128x32 f16) @ wc_tile^T ----
  // xo/wc tiles are contiguous 8 KB blobs with identical [128][64B] geometry.
  {
    const char* xob = (const char*)xo + (size_t)bm0 * 64;
    const char* wcb = (const char*)wc + (size_t)bn0 * 64;
    const i32x4 xs0 = *(const i32x4*)(xob + idx0 * 16);
    const i32x4 xs1 = *(const i32x4*)(xob + idx1 * 16);
    const i32x4 ws0 = *(const i32x4*)(wcb + idx0 * 16);
    const i32x4 ws1 = *(const i32x4*)(wcb + idx1 * 16);
    __syncthreads();
    *(i32x4*)(lA + w0) = xs0;
    *(i32x4*)(lA + w1) = xs1;
    *(i32x4*)(lB + w0) = ws0;
    *(i32x4*)(lB + w1) = ws1;
    __syncthreads();
  }
  f32x4 corr[4][4];
#pragma unroll
  for (int i = 0; i < 4; ++i)
#pragma unroll
    for (int j = 0; j < 4; ++j) corr[i][j] = f32x4{0.f, 0.f, 0.f, 0.f};
  {
    half8 xf[4], wf[4];
#pragma unroll
    for (int i = 0; i < 4; ++i) {
      xf[i] = __builtin_bit_cast(half8, *(const i32x4*)(lA + roA[i]));
      wf[i] = __builtin_bit_cast(half8, *(const i32x4*)(lB + roB[i]));
    }
#pragma unroll
    for (int i = 0; i < 4; ++i)
#pragma unroll
      for (int j = 0; j < 4; ++j)
        corr[i][j] = __builtin_amdgcn_mfma_f32_16x16x32_f16(xf[i], wf[j], corr[i][j], 0, 0, 0);
  }

  // ---- epilogue: y = acc*srow*wscale + bias + corr, store f32 ----
#pragma unroll
  for (int i = 0; i < 4; ++i) {
    const int rowg = bm0 + wm * 64 + i * 16 + (lane >> 4) * 4;
    const f32x4 sr = *(const f32x4*)(srow + rowg);
#pragma unroll
    for (int j = 0; j < 4; ++j) {
      const int colg = bn0 + wn * 64 + j * 16 + (lane & 15);
      const float2 scb = ((const float2*)sc)[colg];  // [scale, bias]
      float* op = out + (size_t)rowg * NTOT + colg;
#pragma unroll
      for (int r = 0; r < 4; ++r) {
        const float y = (float)acc[i][j][r] * (sr[r] * scb.x) + scb.y + corr[i][j][r];
        op[(size_t)r * NTOT] = y;
      }
    }
  }
}

extern "C" void kernel_launch(void* const* d_in, const int* in_sizes, int n_in,
                              void* d_out, int out_size, void* d_ws, size_t ws_size,
                              hipStream_t stream) {
  (void)in_sizes; (void)n_in; (void)out_size; (void)ws_size;
  const float* x    = (const float*)d_in[0];   // f32 [2,4096,4096] (fp16 values)
  const int*   qw32 = (const int*)d_in[1];     // int32 [4096,4096] (int8 values)
  const float* sc   = (const float*)d_in[2];   // f32 [4096,2] (scale,bias)
  const float* wcf  = (const float*)d_in[3];   // f32 [4096,32]
  const int*   ind  = (const int*)d_in[4];     // int32 [32]
  float* out = (float*)d_out;

  char* ws = (char*)d_ws;
  int8_t*   qx   = (int8_t*)ws;                          // 32 MB
  float*    srow = (float*)(ws + 33554432);              // 32 KB
  _Float16* xo   = (_Float16*)(ws + 33587200);           // 512 KB
  int8_t*   qw8  = (int8_t*)(ws + 34111488);             // 16 MB
  _Float16* wch  = (_Float16*)(ws + 50888704);           // 256 KB

  pack_kernel<<<4096 + 128, 256, 0, stream>>>(qw32, qw8, wcf, wch);
  quant_kernel<<<MTOT, 256, 0, stream>>>(x, ind, qx, srow, xo);
  mixgemm_kernel<<<(MTOT / 128) * (NTOT / 128), 256, 0, stream>>>(qx, qw8, srow, sc, xo, wch, out);
}

// Round 5
// 446.894 us; speedup vs baseline: 1.0407x; 1.0407x over previous
//
#include <hip/hip_runtime.h>
#include <stdint.h>

// MixLinear (LLM.int8-style): dynamic per-row quant + int8 MFMA GEMM +
// fused dequant/bias + rank-32 fp16 outlier-correction MFMA.
// R4/R5: mixgemm -> global_load_lds staging (linear dest, inverse-swizzled
// per-lane source, swizzled ds_read), correct (r>>1)&3 bank swizzle,
// XCD-aware block swizzle. quant -> wave-per-row (no barriers, 16x ILP).

typedef float    f32x4  __attribute__((ext_vector_type(4)));
typedef int      i32x4  __attribute__((ext_vector_type(4)));
typedef _Float16 half8  __attribute__((ext_vector_type(8)));
typedef _Float16 half4  __attribute__((ext_vector_type(4)));

#define MTOT 8192
#define NTOT 4096
#define KTOT 4096

// LDS tile geometry: [128 rows][64 B]; 16B chunk (r,c) stored at slot c ^ SWZ(r)
#define SWZ(r) (((r) >> 1) & 3)

static __device__ __forceinline__ void gload16(const int8_t* g, int8_t* l) {
  __builtin_amdgcn_global_load_lds(
      (const __attribute__((address_space(1))) void*)g,
      (__attribute__((address_space(3))) void*)l, 16, 0, 0);
}

// ---------- kernel 0: pack int32 weights -> int8; weight_cache f32 -> f16 ---
__global__ __launch_bounds__(256) void pack_kernel(
    const int* __restrict__ qw32, int8_t* __restrict__ qw8,
    const float* __restrict__ wc, _Float16* __restrict__ wch)
{
  const int bid = blockIdx.x;
  const int t = threadIdx.x;
  if (bid < 4096) {
    const int base = bid * 4096;
#pragma unroll
    for (int g = 0; g < 4; ++g) {
      const int off = g * 1024 + t * 4;
      const i32x4 v = *(const i32x4*)(qw32 + base + off);
      const uint32_t o = (uint32_t)(v[0] & 255) | ((uint32_t)(v[1] & 255) << 8) |
                         ((uint32_t)(v[2] & 255) << 16) | ((uint32_t)(v[3] & 255) << 24);
      *(uint32_t*)(qw8 + base + off) = o;
    }
  } else {
    const int idx = (bid - 4096) * 1024 + t * 4;  // 128 blocks * 1024 = 131072
    const float4 v = *(const float4*)(wc + idx);
    half4 h = {(_Float16)v.x, (_Float16)v.y, (_Float16)v.z, (_Float16)v.w};
    *(half4*)(wch + idx) = h;
  }
}

// ---------- kernel 1: per-row absmax + quantize, one wave per row ----------
__global__ __launch_bounds__(256) void quant_kernel(
    const float* __restrict__ x, const int* __restrict__ ind,
    int8_t* __restrict__ qx, float* __restrict__ srow, _Float16* __restrict__ xo)
{
  const int t = threadIdx.x;
  const int w = t >> 6, l = t & 63;
  const int row = blockIdx.x * 4 + w;
  const float* xrow = x + (size_t)row * KTOT;
  const float4* xr = (const float4*)xrow;

  float4 v[16];
#pragma unroll
  for (int g = 0; g < 16; ++g) v[g] = xr[g * 64 + l];  // fully coalesced, 16-deep ILP

  float am = 0.f;
#pragma unroll
  for (int g = 0; g < 16; ++g)
    am = fmaxf(am, fmaxf(fmaxf(fabsf(v[g].x), fabsf(v[g].y)),
                         fmaxf(fabsf(v[g].z), fabsf(v[g].w))));
#pragma unroll
  for (int off = 32; off; off >>= 1)
    am = fmaxf(am, __shfl_xor(am, off, 64));

  const float rscale = 127.0f / am;
  uint32_t* qrow = (uint32_t*)(qx + (size_t)row * KTOT);
#pragma unroll
  for (int g = 0; g < 16; ++g) {
    const float4 u = v[g];
    const int q0 = (int)rintf(fminf(fmaxf(u.x * rscale, -128.f), 127.f));
    const int q1 = (int)rintf(fminf(fmaxf(u.y * rscale, -128.f), 127.f));
    const int q2 = (int)rintf(fminf(fmaxf(u.z * rscale, -128.f), 127.f));
    const int q3 = (int)rintf(fminf(fmaxf(u.w * rscale, -128.f), 127.f));
    qrow[g * 64 + l] = (uint32_t)(q0 & 255) | ((uint32_t)(q1 & 255) << 8) |
                       ((uint32_t)(q2 & 255) << 16) | ((uint32_t)(q3 & 255) << 24);
  }
  if (l < 32) xo[row * 32 + l] = (_Float16)xrow[ind[l]];
  if (l == 0) srow[row] = am / 127.0f;
}

// ---------- kernel 2: int8 GEMM + dequant + bias + fp16 outlier MFMA -------
// 128x128 tile, 4 waves 2x2, each wave 64x64 via 4x4 mfma_i32_16x16x64_i8.
// Staging: global_load_lds dwordx4, linear LDS dest, source pre-swizzled so
// LDS slot (r, c^SWZ(r)) holds global chunk (r, c).
__global__ __launch_bounds__(256) void mixgemm_kernel(
    const int8_t* __restrict__ qx, const int8_t* __restrict__ qw,
    const float* __restrict__ srow, const float* __restrict__ sc,
    const _Float16* __restrict__ xo, const _Float16* __restrict__ wc,
    float* __restrict__ out)
{
  __shared__ int8_t lA[128 * 64];
  __shared__ int8_t lB[128 * 64];

  const int t = threadIdx.x;
  const int lane = t & 63;
  const int wid = t >> 6;
  const int wm = wid >> 1, wn = wid & 1;

  // XCD-aware bijective swizzle: 2048 blocks = 8 XCDs x 256
  const int bid = blockIdx.x;
  const int swz = (bid & 7) * 256 + (bid >> 3);
  const int tn = swz & 31;   // NTOT/128 = 32
  const int tm = swz >> 5;
  const int bm0 = tm * 128, bn0 = tn * 128;

  // gload_lds staging: wave w fills LDS bytes [w*2048, w*2048+2048) of each
  // tile via 2 instrs (lane l -> base + 16*l). Linear chunk i = w*128+j*64+l,
  // row r = i>>2, slot s = i&3; source chunk col = s ^ SWZ(r).
  const int rst = wid * 32 + (lane >> 2);            // row for j=0 (j=1: +16)
  const int cst = ((lane & 3) ^ SWZ(rst)) * 16;      // SWZ invariant under r+16
  const int8_t* gA0 = qx + (size_t)(bm0 + rst) * KTOT + cst;
  const int8_t* gB0 = qw + (size_t)(bn0 + rst) * KTOT + cst;
  int8_t* dA = lA + wid * 2048;
  int8_t* dB = lB + wid * 2048;

  // fragment ds_read offsets (A rows = wave M strip, B rows = wave N strip)
  int roA[4], roB[4];
#pragma unroll
  for (int i = 0; i < 4; ++i) {
    const int ra = wm * 64 + i * 16 + (lane & 15);
    roA[i] = ra * 64 + (((lane >> 4) ^ SWZ(ra)) * 16);
    const int rb = wn * 64 + i * 16 + (lane & 15);
    roB[i] = rb * 64 + (((lane >> 4) ^ SWZ(rb)) * 16);
  }

  i32x4 acc[4][4];
#pragma unroll
  for (int i = 0; i < 4; ++i)
#pragma unroll
    for (int j = 0; j < 4; ++j) acc[i][j] = i32x4{0, 0, 0, 0};

  for (int kt = 0; kt < KTOT; kt += 64) {
    __syncthreads();  // previous iter's ds_reads done before DMA overwrite
    gload16(gA0 + kt, dA);
    gload16(gA0 + kt + 16 * KTOT, dA + 1024);
    gload16(gB0 + kt, dB);
    gload16(gB0 + kt + 16 * KTOT, dB + 1024);
    __syncthreads();  // compiler drains vmcnt(0) before this barrier
    i32x4 af[4], bfr[4];
#pragma unroll
    for (int i = 0; i < 4; ++i) {
      af[i]  = *(const i32x4*)(lA + roA[i]);
      bfr[i] = *(const i32x4*)(lB + roB[i]);
    }
#pragma unroll
    for (int i = 0; i < 4; ++i)
#pragma unroll
      for (int j = 0; j < 4; ++j)
        acc[i][j] = __builtin_amdgcn_mfma_i32_16x16x64_i8(af[i], bfr[j], acc[i][j], 0, 0, 0);
  }

  // ---- outlier correction: corr = xo_tile (128x32 f16) @ wc_tile^T ----
  // xo/wc tiles are contiguous 8 KB blobs with identical [128][64B] geometry.
  {
    const int idx0 = t, idx1 = t + 256;
    const int r0 = idx0 >> 2, c0 = idx0 & 3;
    const int r1 = idx1 >> 2, c1 = idx1 & 3;
    const int w0 = r0 * 64 + ((c0 ^ SWZ(r0)) * 16);
    const int w1 = r1 * 64 + ((c1 ^ SWZ(r1)) * 16);
    const char* xob = (const char*)xo + (size_t)bm0 * 64;
    const char* wcb = (const char*)wc + (size_t)bn0 * 64;
    const i32x4 xs0 = *(const i32x4*)(xob + idx0 * 16);
    const i32x4 xs1 = *(const i32x4*)(xob + idx1 * 16);
    const i32x4 ws0 = *(const i32x4*)(wcb + idx0 * 16);
    const i32x4 ws1 = *(const i32x4*)(wcb + idx1 * 16);
    __syncthreads();  // last K-step's ds_reads done
    *(i32x4*)(lA + w0) = xs0;
    *(i32x4*)(lA + w1) = xs1;
    *(i32x4*)(lB + w0) = ws0;
    *(i32x4*)(lB + w1) = ws1;
    __syncthreads();
  }
  f32x4 corr[4][4];
#pragma unroll
  for (int i = 0; i < 4; ++i)
#pragma unroll
    for (int j = 0; j < 4; ++j) corr[i][j] = f32x4{0.f, 0.f, 0.f, 0.f};
  {
    half8 xf[4], wf[4];
#pragma unroll
    for (int i = 0; i < 4; ++i) {
      xf[i] = __builtin_bit_cast(half8, *(const i32x4*)(lA + roA[i]));
      wf[i] = __builtin_bit_cast(half8, *(const i32x4*)(lB + roB[i]));
    }
#pragma unroll
    for (int i = 0; i < 4; ++i)
#pragma unroll
      for (int j = 0; j < 4; ++j)
        corr[i][j] = __builtin_amdgcn_mfma_f32_16x16x32_f16(xf[i], wf[j], corr[i][j], 0, 0, 0);
  }

  // ---- epilogue: y = acc*srow*wscale + bias + corr, store f32 ----
#pragma unroll
  for (int i = 0; i < 4; ++i) {
    const int rowg = bm0 + wm * 64 + i * 16 + (lane >> 4) * 4;
    const f32x4 sr = *(const f32x4*)(srow + rowg);
#pragma unroll
    for (int j = 0; j < 4; ++j) {
      const int colg = bn0 + wn * 64 + j * 16 + (lane & 15);
      const float2 scb = ((const float2*)sc)[colg];  // [scale, bias]
      float* op = out + (size_t)rowg * NTOT + colg;
#pragma unroll
      for (int r = 0; r < 4; ++r) {
        const float y = (float)acc[i][j][r] * (sr[r] * scb.x) + scb.y + corr[i][j][r];
        op[(size_t)r * NTOT] = y;
      }
    }
  }
}

extern "C" void kernel_launch(void* const* d_in, const int* in_sizes, int n_in,
                              void* d_out, int out_size, void* d_ws, size_t ws_size,
                              hipStream_t stream) {
  (void)in_sizes; (void)n_in; (void)out_size; (void)ws_size;
  const float* x    = (const float*)d_in[0];   // f32 [2,4096,4096] (fp16 values)
  const int*   qw32 = (const int*)d_in[1];     // int32 [4096,4096] (int8 values)
  const float* sc   = (const float*)d_in[2];   // f32 [4096,2] (scale,bias)
  const float* wcf  = (const float*)d_in[3];   // f32 [4096,32]
  const int*   ind  = (const int*)d_in[4];     // int32 [32]
  float* out = (float*)d_out;

  char* ws = (char*)d_ws;
  int8_t*   qx   = (int8_t*)ws;                          // 32 MB
  float*    srow = (float*)(ws + 33554432);              // 32 KB
  _Float16* xo   = (_Float16*)(ws + 33587200);           // 512 KB
  int8_t*   qw8  = (int8_t*)(ws + 34111488);             // 16 MB
  _Float16* wch  = (_Float16*)(ws + 50888704);           // 256 KB

  pack_kernel<<<4096 + 128, 256, 0, stream>>>(qw32, qw8, wcf, wch);
  quant_kernel<<<MTOT / 4, 256, 0, stream>>>(x, ind, qx, srow, xo);
  mixgemm_kernel<<<(MTOT / 128) * (NTOT / 128), 256, 0, stream>>>(qx, qw8, srow, sc, xo, wch, out);
}